// Round 1
// baseline (2660.889 us; speedup 1.0000x reference)
//
#include <hip/hip_runtime.h>
#include <hip/hip_bf16.h>
#include <cstdint>

#define D_MODEL 2048
#define NH 16
#define HD 128
#define SEQ 2048
#define BATCH 2
#define QKV_LD (3 * D_MODEL) // 6144

typedef __attribute__((ext_vector_type(8))) short short8;
typedef __attribute__((ext_vector_type(4))) float f32x4;

__device__ __forceinline__ ushort f2bf(float f) {
    union { float f; uint32_t u; } c; c.f = f;
    uint32_t u = c.u;
    uint32_t r = (u + 0x7FFFu + ((u >> 16) & 1u)) >> 16;
    return (ushort)r;
}

// ---------------- fp32 -> bf16 cast (x) ----------------
__global__ void cvt_bf16_kernel(const float* __restrict__ in, ushort* __restrict__ out, int n4) {
    int idx = blockIdx.x * blockDim.x + threadIdx.x;
    if (idx >= n4) return;
    float4 v = ((const float4*)in)[idx];
    ushort4 o;
    o.x = f2bf(v.x); o.y = f2bf(v.y); o.z = f2bf(v.z); o.w = f2bf(v.w);
    ((ushort4*)out)[idx] = o;
}

// ---------------- fp32 [R][C] -> bf16 [C][R] transpose ----------------
__global__ void transpose_bf16_kernel(const float* __restrict__ in, ushort* __restrict__ out,
                                      int R, int C) {
    __shared__ float tile[32][33];
    int tx = threadIdx.x, ty = threadIdx.y; // 32 x 8
    int c0 = blockIdx.x * 32, r0 = blockIdx.y * 32;
    for (int i = 0; i < 4; ++i) {
        int r = r0 + ty + i * 8;
        tile[ty + i * 8][tx] = in[(size_t)r * C + c0 + tx];
    }
    __syncthreads();
    for (int i = 0; i < 4; ++i) {
        int c = c0 + ty + i * 8;
        out[(size_t)c * R + r0 + tx] = f2bf(tile[tx][ty + i * 8]);
    }
}

// ---------------- bf16 MFMA GEMM: C[M][N] = A[M][K] * Bt[N][K]^T + bias ----------------
// 128x128 tile, BK=32, 256 threads (4 waves, each 64x64 = 4x4 MFMA accs)
__global__ __launch_bounds__(256) void gemm_bt_bias(
    const ushort* __restrict__ A,   // [M][K] bf16
    const ushort* __restrict__ Bt,  // [N][K] bf16 (pre-transposed B)
    const float* __restrict__ bias, // [N]
    float* __restrict__ C,          // [M][N] fp32
    int M, int N, int K)
{
    __shared__ ushort As[128 * 32];
    __shared__ ushort Bs[128 * 32];
    int t = threadIdx.x;
    int m0 = blockIdx.y * 128, n0 = blockIdx.x * 128;
    int wave = t >> 6, lane = t & 63;
    int wm = (wave & 1) * 64, wn = (wave >> 1) * 64;
    int lr = lane & 15, lh = lane >> 4;

    f32x4 acc[4][4];
    for (int i = 0; i < 4; i++)
        for (int j = 0; j < 4; j++)
            acc[i][j] = (f32x4)0.0f;

    int srow = t >> 2;        // 0..63
    int scol = (t & 3) * 8;   // 0,8,16,24
    const ushort* Ag = A + (size_t)(m0 + srow) * K + scol;
    const ushort* Bg = Bt + (size_t)(n0 + srow) * K + scol;

    for (int k0 = 0; k0 < K; k0 += 32) {
        __syncthreads();
        {
            uint4 a0 = *(const uint4*)(Ag + k0);
            uint4 a1 = *(const uint4*)(Ag + (size_t)64 * K + k0);
            uint4 b0 = *(const uint4*)(Bg + k0);
            uint4 b1 = *(const uint4*)(Bg + (size_t)64 * K + k0);
            *(uint4*)(As + srow * 32 + scol) = a0;
            *(uint4*)(As + (srow + 64) * 32 + scol) = a1;
            *(uint4*)(Bs + srow * 32 + scol) = b0;
            *(uint4*)(Bs + (srow + 64) * 32 + scol) = b1;
        }
        __syncthreads();
        short8 a[4], b[4];
        for (int i = 0; i < 4; i++)
            a[i] = *(const short8*)(As + (wm + i * 16 + lr) * 32 + lh * 8);
        for (int j = 0; j < 4; j++)
            b[j] = *(const short8*)(Bs + (wn + j * 16 + lr) * 32 + lh * 8);
        for (int i = 0; i < 4; i++)
            for (int j = 0; j < 4; j++)
                acc[i][j] = __builtin_amdgcn_mfma_f32_16x16x32_bf16(a[i], b[j], acc[i][j], 0, 0, 0);
    }

    for (int i = 0; i < 4; i++) {
        int row = m0 + wm + i * 16 + lh * 4;
        for (int j = 0; j < 4; j++) {
            int col = n0 + wn + j * 16 + lr;
            float bv = bias[col];
            for (int r = 0; r < 4; r++) {
                C[(size_t)(row + r) * N + col] = acc[i][j][r] + bv;
            }
        }
    }
}

// ---------------- RoPE in-place on q,k of qkv [B*S][6144] ----------------
// one wave per 128-dim head vector; lane j handles out[j], out[64+j]
__global__ void rope_kernel(float* __restrict__ qkv) {
    int t = threadIdx.x;
    int wv = blockIdx.x * 4 + (t >> 6); // vector id, 0..131071
    int j = t & 63;
    int bs = wv >> 5;        // b*2048 + s
    int rem = wv & 31;
    int which = rem >> 4;    // 0=q, 1=k
    int h = rem & 15;
    int s = bs & 2047;
    size_t base = (size_t)bs * QKV_LD + which * D_MODEL + h * HD;
    float2 xv = *(const float2*)(qkv + base + 2 * j);
    float theta = powf(10000.0f, -(float)j * (1.0f / 64.0f));
    float ang = (float)s * theta;
    float sn, cs;
    sincosf(ang, &sn, &cs);
    // wave-lockstep: all lanes load before any lane stores (data-dep on load)
    qkv[base + j]      = xv.x * cs - xv.y * sn;
    qkv[base + 64 + j] = xv.x * sn + xv.y * cs;
}

// ---------------- flash attention fp32: 64q x 64k tiles, online softmax ----------------
__global__ __launch_bounds__(256) void attn_kernel(const float* __restrict__ qkv,
                                                   ushort* __restrict__ ctx) {
    __shared__ float Qs[64][132];
    __shared__ float Ks[64][36];
    __shared__ float Vs[16][132];
    __shared__ float Ps[64][68];
    __shared__ float red[64][17];
    __shared__ float m_run[64], l_run[64], alpha_s[64], m_new[64];

    int t = threadIdx.x;
    int ty = t >> 4, tx = t & 15;
    int q0 = blockIdx.x * 64;
    int bh = blockIdx.y;
    int b = bh >> 4, h = bh & 15;
    size_t tokbase = (size_t)b * SEQ;

    // Q tile 64x128 resident in LDS
    for (int p = 0; p < 8; ++p) {
        int flat = p * 1024 + t * 4;
        int r = flat >> 7, d = flat & 127;
        float4 v = *(const float4*)(qkv + (tokbase + q0 + r) * (size_t)QKV_LD + h * HD + d);
        *(float4*)&Qs[r][d] = v;
    }
    if (t < 64) { m_run[t] = -INFINITY; l_run[t] = 0.0f; }
    float O[4][8];
    for (int i = 0; i < 4; i++)
        for (int jd = 0; jd < 8; jd++) O[i][jd] = 0.0f;

    const float scale = 0.08838834764831845f; // 1/sqrt(128)

    for (int k0 = 0; k0 < SEQ; k0 += 64) {
        float s[4][4];
        for (int i = 0; i < 4; i++)
            for (int j = 0; j < 4; j++) s[i][j] = 0.0f;

        // scores: S = Q K^T, d-chunks of 32
        for (int dc = 0; dc < 4; ++dc) {
            __syncthreads();
            for (int p = 0; p < 2; ++p) {
                int flat = p * 1024 + t * 4;
                int r = flat >> 5, d = flat & 31;
                float4 v = *(const float4*)(qkv + (tokbase + k0 + r) * (size_t)QKV_LD
                                            + D_MODEL + h * HD + dc * 32 + d);
                *(float4*)&Ks[r][d] = v;
            }
            __syncthreads();
            for (int d4 = 0; d4 < 8; ++d4) {
                float4 qv[4], kv[4];
                for (int i = 0; i < 4; i++) qv[i] = *(const float4*)&Qs[ty * 4 + i][dc * 32 + d4 * 4];
                for (int j = 0; j < 4; j++) kv[j] = *(const float4*)&Ks[tx * 4 + j][d4 * 4];
                for (int i = 0; i < 4; i++)
                    for (int j = 0; j < 4; j++)
                        s[i][j] += qv[i].x * kv[j].x + qv[i].y * kv[j].y
                                 + qv[i].z * kv[j].z + qv[i].w * kv[j].w;
            }
        }

        // row-max partial reduction
        float rm[4];
        for (int i = 0; i < 4; i++) {
            rm[i] = -INFINITY;
            for (int j = 0; j < 4; j++) { s[i][j] *= scale; rm[i] = fmaxf(rm[i], s[i][j]); }
            red[ty * 4 + i][tx] = rm[i];
        }
        __syncthreads();
        if (t < 64) {
            float mx = -INFINITY;
            for (int c = 0; c < 16; c++) mx = fmaxf(mx, red[t][c]);
            float mo = m_run[t];
            float mn = fmaxf(mo, mx);
            m_run[t] = mn;
            m_new[t] = mn;
            alpha_s[t] = __expf(mo - mn); // exp(-inf)=0 on first tile
        }
        __syncthreads();

        // P = exp(S - m), O-rescale, partial row sums
        for (int i = 0; i < 4; i++) {
            int r = ty * 4 + i;
            float mn = m_new[r];
            float a = alpha_s[r];
            float4 p4;
            p4.x = __expf(s[i][0] - mn);
            p4.y = __expf(s[i][1] - mn);
            p4.z = __expf(s[i][2] - mn);
            p4.w = __expf(s[i][3] - mn);
            *(float4*)&Ps[r][tx * 4] = p4;
            red[r][tx] = p4.x + p4.y + p4.z + p4.w;
            for (int jd = 0; jd < 8; jd++) O[i][jd] *= a;
        }
        __syncthreads();
        if (t < 64) {
            float sm = 0.0f;
            for (int c = 0; c < 16; c++) sm += red[t][c];
            l_run[t] = alpha_s[t] * l_run[t] + sm;
        }

        // O += P V, key chunks of 16
        for (int kc = 0; kc < 4; ++kc) {
            __syncthreads();
            for (int p = 0; p < 2; ++p) {
                int flat = p * 1024 + t * 4;
                int r = flat >> 7, d = flat & 127;
                float4 v = *(const float4*)(qkv + (tokbase + k0 + kc * 16 + r) * (size_t)QKV_LD
                                            + 2 * D_MODEL + h * HD + d);
                *(float4*)&Vs[r][d] = v;
            }
            __syncthreads();
            for (int k = 0; k < 16; ++k) {
                float pv[4];
                for (int i = 0; i < 4; i++) pv[i] = Ps[ty * 4 + i][kc * 16 + k];
                float4 v0 = *(const float4*)&Vs[k][tx * 8];
                float4 v1 = *(const float4*)&Vs[k][tx * 8 + 4];
                for (int i = 0; i < 4; i++) {
                    O[i][0] += pv[i] * v0.x; O[i][1] += pv[i] * v0.y;
                    O[i][2] += pv[i] * v0.z; O[i][3] += pv[i] * v0.w;
                    O[i][4] += pv[i] * v1.x; O[i][5] += pv[i] * v1.y;
                    O[i][6] += pv[i] * v1.z; O[i][7] += pv[i] * v1.w;
                }
            }
        }
    }

    __syncthreads();
    for (int i = 0; i < 4; i++) {
        int r = ty * 4 + i;
        float inv = 1.0f / l_run[r];
        union { ushort u[8]; uint4 v; } pk;
        for (int jd = 0; jd < 8; jd++) pk.u[jd] = f2bf(O[i][jd] * inv);
        size_t idx = (tokbase + q0 + r) * (size_t)D_MODEL + h * HD + tx * 8;
        *(uint4*)(ctx + idx) = pk.v;
    }
}

extern "C" void kernel_launch(void* const* d_in, const int* in_sizes, int n_in,
                              void* d_out, int out_size, void* d_ws, size_t ws_size,
                              hipStream_t stream) {
    const float* x    = (const float*)d_in[0];
    const float* Wqkv = (const float*)d_in[1];
    const float* bqkv = (const float*)d_in[2];
    const float* Wo   = (const float*)d_in[3];
    const float* bo   = (const float*)d_in[4];
    float* out = (float*)d_out;

    char* ws = (char*)d_ws;
    ushort* x_bf  = (ushort*)(ws);                 // 16 MB: [4096][2048] bf16
    ushort* wqkvT = (ushort*)(ws + 16777216);      // 24 MB: [6144][2048] bf16
    ushort* woT   = (ushort*)(ws + 41943040);      //  8 MB: [2048][2048] bf16
    float*  qkv   = (float*)(ws + 50331648);       // 96 MB: [4096][6144] fp32
    ushort* ctx   = (ushort*)(ws + 150994944);     // 16 MB: [4096][2048] bf16
    // total 160 MB

    // 1. x -> bf16
    cvt_bf16_kernel<<<8192, 256, 0, stream>>>(x, x_bf, 2097152);
    // 2. Wqkv [2048][6144] -> [6144][2048] bf16 ; Wo likewise
    transpose_bf16_kernel<<<dim3(192, 64), dim3(32, 8), 0, stream>>>(Wqkv, wqkvT, 2048, 6144);
    transpose_bf16_kernel<<<dim3(64, 64), dim3(32, 8), 0, stream>>>(Wo, woT, 2048, 2048);
    // 3. qkv = x @ Wqkv + bqkv   (M=4096, N=6144, K=2048)
    gemm_bt_bias<<<dim3(48, 32), 256, 0, stream>>>(x_bf, wqkvT, bqkv, qkv, 4096, 6144, 2048);
    // 4. RoPE in-place on q,k
    rope_kernel<<<32768, 256, 0, stream>>>(qkv);
    // 5. attention -> ctx (bf16)
    attn_kernel<<<dim3(32, 32), 256, 0, stream>>>(qkv, ctx);
    // 6. out = ctx @ Wo + bo   (M=4096, N=2048, K=2048)
    gemm_bt_bias<<<dim3(16, 32), 256, 0, stream>>>(ctx, woT, bo, out, 4096, 2048, 2048);
}

// Round 2
// 481.554 us; speedup vs baseline: 5.5256x; 5.5256x over previous
//
#include <hip/hip_runtime.h>
#include <hip/hip_bf16.h>
#include <cstdint>
#include <type_traits>

#define D_MODEL 2048
#define NH 16
#define HD 128
#define SEQ 2048
#define QKV_LD (3 * D_MODEL) // 6144

typedef __attribute__((ext_vector_type(8))) short short8;
typedef __attribute__((ext_vector_type(4))) float f32x4;
typedef __attribute__((ext_vector_type(16))) float f32x16;

__device__ __forceinline__ ushort f2bf(float f) {
    union { float f; uint32_t u; } c; c.f = f;
    uint32_t u = c.u;
    uint32_t r = (u + 0x7FFFu + ((u >> 16) & 1u)) >> 16;
    return (ushort)r;
}
__device__ __forceinline__ float bf2f(ushort b) {
    union { uint32_t u; float f; } c; c.u = ((uint32_t)b) << 16;
    return c.f;
}

// ---------------- fp32 -> bf16 cast (x) ----------------
__global__ void cvt_bf16_kernel(const float* __restrict__ in, ushort* __restrict__ out, int n4) {
    int idx = blockIdx.x * blockDim.x + threadIdx.x;
    if (idx >= n4) return;
    float4 v = ((const float4*)in)[idx];
    ushort4 o;
    o.x = f2bf(v.x); o.y = f2bf(v.y); o.z = f2bf(v.z); o.w = f2bf(v.w);
    ((ushort4*)out)[idx] = o;
}

// ---------------- fp32 [R][C] -> bf16 [C][R] transpose ----------------
__global__ void transpose_bf16_kernel(const float* __restrict__ in, ushort* __restrict__ out,
                                      int R, int C) {
    __shared__ float tile[32][33];
    int tx = threadIdx.x, ty = threadIdx.y; // 32 x 8
    int c0 = blockIdx.x * 32, r0 = blockIdx.y * 32;
    for (int i = 0; i < 4; ++i) {
        int r = r0 + ty + i * 8;
        tile[ty + i * 8][tx] = in[(size_t)r * C + c0 + tx];
    }
    __syncthreads();
    for (int i = 0; i < 4; ++i) {
        int c = c0 + ty + i * 8;
        out[(size_t)c * R + r0 + tx] = f2bf(tile[tx][ty + i * 8]);
    }
}

// ---------------- bf16 MFMA GEMM: C[M][N] = A[M][K] * Bt[N][K]^T + bias ----------------
template <typename OutT>
__global__ __launch_bounds__(256) void gemm_bt_bias(
    const ushort* __restrict__ A,   // [M][K] bf16
    const ushort* __restrict__ Bt,  // [N][K] bf16
    const float* __restrict__ bias, // [N]
    OutT* __restrict__ C,           // [M][N] fp32 or bf16
    int M, int N, int K)
{
    __shared__ ushort As[128 * 32];
    __shared__ ushort Bs[128 * 32];
    int t = threadIdx.x;
    int m0 = blockIdx.y * 128, n0 = blockIdx.x * 128;
    int wave = t >> 6, lane = t & 63;
    int wm = (wave & 1) * 64, wn = (wave >> 1) * 64;
    int lr = lane & 15, lh = lane >> 4;

    f32x4 acc[4][4];
    for (int i = 0; i < 4; i++)
        for (int j = 0; j < 4; j++)
            acc[i][j] = (f32x4)0.0f;

    int srow = t >> 2;
    int scol = (t & 3) * 8;
    const ushort* Ag = A + (size_t)(m0 + srow) * K + scol;
    const ushort* Bg = Bt + (size_t)(n0 + srow) * K + scol;

    for (int k0 = 0; k0 < K; k0 += 32) {
        __syncthreads();
        {
            uint4 a0 = *(const uint4*)(Ag + k0);
            uint4 a1 = *(const uint4*)(Ag + (size_t)64 * K + k0);
            uint4 b0 = *(const uint4*)(Bg + k0);
            uint4 b1 = *(const uint4*)(Bg + (size_t)64 * K + k0);
            *(uint4*)(As + srow * 32 + scol) = a0;
            *(uint4*)(As + (srow + 64) * 32 + scol) = a1;
            *(uint4*)(Bs + srow * 32 + scol) = b0;
            *(uint4*)(Bs + (srow + 64) * 32 + scol) = b1;
        }
        __syncthreads();
        short8 a[4], b[4];
        for (int i = 0; i < 4; i++)
            a[i] = *(const short8*)(As + (wm + i * 16 + lr) * 32 + lh * 8);
        for (int j = 0; j < 4; j++)
            b[j] = *(const short8*)(Bs + (wn + j * 16 + lr) * 32 + lh * 8);
        for (int i = 0; i < 4; i++)
            for (int j = 0; j < 4; j++)
                acc[i][j] = __builtin_amdgcn_mfma_f32_16x16x32_bf16(a[i], b[j], acc[i][j], 0, 0, 0);
    }

    for (int i = 0; i < 4; i++) {
        int row = m0 + wm + i * 16 + lh * 4;
        for (int j = 0; j < 4; j++) {
            int col = n0 + wn + j * 16 + lr;
            float bv = bias[col];
            for (int r = 0; r < 4; r++) {
                float v = acc[i][j][r] + bv;
                if constexpr (std::is_same<OutT, ushort>::value)
                    C[(size_t)(row + r) * N + col] = f2bf(v);
                else
                    C[(size_t)(row + r) * N + col] = v;
            }
        }
    }
}

// ---------------- RoPE + cast + reshape: qkv_bf16 -> Qb,Kb [bh][s][128] ----------------
// Q gets pre-scaled by 1/sqrt(HD). One wave per 128-dim head vector.
__global__ void rope_cast_qk(const ushort* __restrict__ qkv,
                             ushort* __restrict__ Qb, ushort* __restrict__ Kb) {
    int t = threadIdx.x;
    int wv = blockIdx.x * 4 + (t >> 6); // 0..131071
    int j = t & 63;
    int bs = wv >> 5;
    int rem = wv & 31;
    int which = rem >> 4;  // 0=q, 1=k
    int h = rem & 15;
    int s = bs & 2047;
    int b = bs >> 11;
    size_t src = (size_t)bs * QKV_LD + which * D_MODEL + h * HD;
    uint32_t pr = *(const uint32_t*)(qkv + src + 2 * j);
    float x1 = bf2f((ushort)(pr & 0xffff));
    float x2 = bf2f((ushort)(pr >> 16));
    float theta = powf(10000.0f, -(float)j * (1.0f / 64.0f));
    float ang = (float)s * theta;
    float sn, cs;
    sincosf(ang, &sn, &cs);
    float sc = which ? 1.0f : 0.08838834764831845f; // fold 1/sqrt(128) into Q
    float o1 = (x1 * cs - x2 * sn) * sc;
    float o2 = (x1 * sn + x2 * cs) * sc;
    ushort* dst = which ? Kb : Qb;
    size_t obase = ((size_t)(b * NH + h) * SEQ + s) * HD;
    dst[obase + j] = f2bf(o1);
    dst[obase + 64 + j] = f2bf(o2);
}

// ---------------- V transpose: qkv_bf16 v-part -> Vt [bh][d=128][s=2048] ----------------
__global__ void v_transpose(const ushort* __restrict__ qkv, ushort* __restrict__ Vt) {
    __shared__ ushort tile[32][33];
    int tx = threadIdx.x, ty = threadIdx.y; // 32 x 8
    int s0 = blockIdx.x * 32;
    int d0 = blockIdx.y * 32;
    int bh = blockIdx.z;
    int b = bh >> 4, h = bh & 15;
    for (int i = 0; i < 4; ++i) {
        int s = s0 + ty + i * 8;
        tile[ty + i * 8][tx] = qkv[((size_t)(b * SEQ + s)) * QKV_LD + 2 * D_MODEL + h * HD + d0 + tx];
    }
    __syncthreads();
    for (int i = 0; i < 4; ++i) {
        int d = d0 + ty + i * 8;
        Vt[((size_t)bh * HD + d) * SEQ + s0 + tx] = tile[tx][ty + i * 8];
    }
}

// ---------------- MFMA flash attention ----------------
// Block: 256 thr / 4 waves, q-tile 128 (wave w owns 32 q), key-tile 64, one (b,h).
// S^T = K·Q^T via mfma_32x32x16 => q in lanes, keys in regs => register softmax.
// PV as O^T = V^T·P^T: A-frags = Vt rows, B-frags = P[q][k] rows (both contiguous).
__global__ __launch_bounds__(256) void attn_mfma(const ushort* __restrict__ Qb,
                                                 const ushort* __restrict__ Kb,
                                                 const ushort* __restrict__ Vt,
                                                 ushort* __restrict__ ctx) {
    __shared__ ushort smem[25600]; // Ks[0,8192) Vts[8192,16384) Ps[16384,25600)
    ushort* Ks = smem;          // [64][128], 16B chunks swizzled: c' = c ^ (row&15)
    ushort* Vts = smem + 8192;  // [128][64], 16B chunks swizzled: c' = c ^ (row&7)
    ushort* Ps = smem + 16384;  // [128][72] (pad 8 => 144B rows, 16B aligned)

    int t = threadIdx.x;
    int w = t >> 6, l = t & 63;
    int l31 = l & 31, g = l >> 5;
    int q0 = blockIdx.x * 128;
    int bh = blockIdx.y;
    int b = bh >> 4, h = bh & 15;

    int qrow = q0 + w * 32 + l31;
    const ushort* Qg = Qb + ((size_t)bh * SEQ + qrow) * HD;
    short8 qf[8];
#pragma unroll
    for (int kc = 0; kc < 8; kc++)
        qf[kc] = *(const short8*)(Qg + kc * 16 + g * 8);

    f32x16 O[4];
#pragma unroll
    for (int di = 0; di < 4; di++) O[di] = (f32x16)0.0f;
    float m_run = -INFINITY, l_run = 0.0f;

    const ushort* KgB = Kb + (size_t)bh * SEQ * HD;
    const ushort* VtB = Vt + (size_t)bh * HD * SEQ;

    for (int k0 = 0; k0 < SEQ; k0 += 64) {
        __syncthreads();
        // stage K tile 64x128 (16 KB): 4 x uint4 per thread, swizzled chunks
#pragma unroll
        for (int c2 = 0; c2 < 4; c2++) {
            int f = c2 * 256 + t;
            int r = f >> 4, c = f & 15;
            int cp = c ^ (r & 15);
            uint4 v = *(const uint4*)(KgB + (size_t)(k0 + r) * HD + c * 8);
            *(uint4*)(Ks + r * 128 + cp * 8) = v;
        }
        // stage Vt tile 128x64 (16 KB)
#pragma unroll
        for (int c2 = 0; c2 < 4; c2++) {
            int f = c2 * 256 + t;
            int d = f >> 3, c = f & 7;
            int cp = c ^ (d & 7);
            uint4 v = *(const uint4*)(VtB + (size_t)d * SEQ + k0 + c * 8);
            *(uint4*)(Vts + d * 64 + cp * 8) = v;
        }
        __syncthreads();

        // S^T = K · Q^T : per wave [64 keys][32 q] as 2 tiles of 32x32
        f32x16 St[2];
        St[0] = (f32x16)0.0f;
        St[1] = (f32x16)0.0f;
#pragma unroll
        for (int ki = 0; ki < 2; ki++) {
            int row = ki * 32 + l31;
#pragma unroll
            for (int kc = 0; kc < 8; kc++) {
                int cp = (kc * 2 + g) ^ (row & 15);
                short8 a = *(const short8*)(Ks + row * 128 + cp * 8);
                St[ki] = __builtin_amdgcn_mfma_f32_32x32x16_bf16(a, qf[kc], St[ki], 0, 0, 0);
            }
        }

        // online softmax: this lane's q = q0+w*32+l31; keys live in regs
        float mx = -INFINITY;
#pragma unroll
        for (int ki = 0; ki < 2; ki++)
#pragma unroll
            for (int r = 0; r < 16; r++) mx = fmaxf(mx, St[ki][r]);
        mx = fmaxf(mx, __shfl_xor(mx, 32));
        float mn = fmaxf(m_run, mx);
        float alpha = __expf(m_run - mn);
        m_run = mn;
        float psum = 0.0f;
#pragma unroll
        for (int ki = 0; ki < 2; ki++)
#pragma unroll
            for (int r = 0; r < 16; r++) {
                float p = __expf(St[ki][r] - mn);
                St[ki][r] = p;
                psum += p;
            }
        psum += __shfl_xor(psum, 32);
        l_run = l_run * alpha + psum;
#pragma unroll
        for (int di = 0; di < 4; di++)
#pragma unroll
            for (int r = 0; r < 16; r++) O[di][r] *= alpha;

        // P (bf16) -> LDS, wave-private rows; reg-quads = 4 consecutive keys => b64 writes
        {
            int qloc = w * 32 + l31;
            ushort* Pr = Ps + qloc * 72;
#pragma unroll
            for (int ki = 0; ki < 2; ki++)
#pragma unroll
                for (int u = 0; u < 4; u++) {
                    ushort4 pk;
                    pk.x = f2bf(St[ki][4 * u + 0]);
                    pk.y = f2bf(St[ki][4 * u + 1]);
                    pk.z = f2bf(St[ki][4 * u + 2]);
                    pk.w = f2bf(St[ki][4 * u + 3]);
                    *(ushort4*)(Pr + ki * 32 + 8 * u + 4 * g) = pk;
                }
        }

        // O^T += V^T · P^T : per wave [128 d][32 q] as 4 tiles of 32x32, kk = 64/16 = 4
        {
            int qloc = w * 32 + l31;
            short8 pb[4];
#pragma unroll
            for (int kc = 0; kc < 4; kc++)
                pb[kc] = *(const short8*)(Ps + qloc * 72 + kc * 16 + g * 8);
#pragma unroll
            for (int di = 0; di < 4; di++) {
                int d = di * 32 + l31;
#pragma unroll
                for (int kc = 0; kc < 4; kc++) {
                    int cp = (kc * 2 + g) ^ (d & 7);
                    short8 va = *(const short8*)(Vts + d * 64 + cp * 8);
                    O[di] = __builtin_amdgcn_mfma_f32_32x32x16_bf16(va, pb[kc], O[di], 0, 0, 0);
                }
            }
        }
    }

    // epilogue: normalize, transpose through LDS (reuse Ks/Vts region), coalesced store
    __syncthreads();
    float inv = 1.0f / l_run;
    ushort* ob = smem; // [128][128] rows = block-local q
    {
        int qloc = w * 32 + l31;
        ushort* orow = ob + qloc * 128;
#pragma unroll
        for (int di = 0; di < 4; di++)
#pragma unroll
            for (int u = 0; u < 4; u++) {
                ushort4 pk;
                pk.x = f2bf(O[di][4 * u + 0] * inv);
                pk.y = f2bf(O[di][4 * u + 1] * inv);
                pk.z = f2bf(O[di][4 * u + 2] * inv);
                pk.w = f2bf(O[di][4 * u + 3] * inv);
                *(ushort4*)(orow + di * 32 + 8 * u + 4 * g) = pk;
            }
    }
    // wave-private readback (rows w*32..w*32+31) -> coalesced 256B global rows
#pragma unroll
    for (int p = 0; p < 8; p++) {
        int qloc = w * 32 + p * 4 + (l >> 4);
        int c16 = l & 15;
        uint4 v = *(const uint4*)(ob + qloc * 128 + c16 * 8);
        size_t tok = (size_t)b * SEQ + q0 + qloc;
        *(uint4*)(ctx + tok * D_MODEL + h * HD + c16 * 8) = v;
    }
}

extern "C" void kernel_launch(void* const* d_in, const int* in_sizes, int n_in,
                              void* d_out, int out_size, void* d_ws, size_t ws_size,
                              hipStream_t stream) {
    const float* x    = (const float*)d_in[0];
    const float* Wqkv = (const float*)d_in[1];
    const float* bqkv = (const float*)d_in[2];
    const float* Wo   = (const float*)d_in[3];
    const float* bo   = (const float*)d_in[4];
    float* out = (float*)d_out;

    char* ws = (char*)d_ws;
    ushort* x_bf   = (ushort*)(ws);                  // 16 MB [0,16M)
    ushort* wqkvT  = (ushort*)(ws + 16777216);       // 24 MB
    ushort* woT    = (ushort*)(ws + 41943040);       //  8 MB
    ushort* qkv_bf = (ushort*)(ws + 50331648);       // 48 MB: [4096][6144] bf16
    ushort* Qb     = (ushort*)(ws + 100663296);      // 16 MB: [32][2048][128] bf16
    ushort* Kb     = (ushort*)(ws + 117440512);      // 16 MB
    ushort* VtG    = (ushort*)(ws + 134217728);      // 16 MB: [32][128][2048] bf16
    ushort* ctx    = (ushort*)(ws + 150994944);      // 16 MB -> total 160 MB

    cvt_bf16_kernel<<<8192, 256, 0, stream>>>(x, x_bf, 2097152);
    transpose_bf16_kernel<<<dim3(192, 64), dim3(32, 8), 0, stream>>>(Wqkv, wqkvT, 2048, 6144);
    transpose_bf16_kernel<<<dim3(64, 64), dim3(32, 8), 0, stream>>>(Wo, woT, 2048, 2048);
    // qkv = x @ Wqkv + bqkv  -> bf16
    gemm_bt_bias<ushort><<<dim3(48, 32), 256, 0, stream>>>(x_bf, wqkvT, bqkv, qkv_bf, 4096, 6144, 2048);
    // RoPE + reshape q,k ; transpose v
    rope_cast_qk<<<32768, 256, 0, stream>>>(qkv_bf, Qb, Kb);
    v_transpose<<<dim3(64, 4, 32), dim3(32, 8), 0, stream>>>(qkv_bf, VtG);
    // MFMA flash attention -> ctx bf16
    attn_mfma<<<dim3(16, 32), 256, 0, stream>>>(Qb, Kb, VtG, ctx);
    // out = ctx @ Wo + bo
    gemm_bt_bias<float><<<dim3(16, 32), 256, 0, stream>>>(ctx, woT, bo, out, 4096, 2048, 2048);
}